// Round 17
// baseline (233.366 us; speedup 1.0000x reference)
//
#include <hip/hip_runtime.h>
#include <stdint.h>

// Koopman autoencoder — round 17 (MI355X / gfx950).
// Dual-stream blocks: 512 thr / 8 waves (32x32 per wave), 1 block/CU,
// two independent MFMA chains per phase (dec(pe)||dec(pd), predstep0||step1,
// encTileA||encTileB). Pinned weights, direct f4 stores, relaxed tickets.

typedef _Float16 h8 __attribute__((ext_vector_type(8)));
typedef _Float16 h4 __attribute__((ext_vector_type(4)));
typedef float    f4 __attribute__((ext_vector_type(4)));

#define ROWS_AUTO 104448
#define NT64      1632           // 64-row tiles
#define NPAIR     816            // enc pair-units
#define NUNITS    2432           // 1632 dec + 800 pred (32 rtiles x 25 chunks x 2 steps)

// half-element offsets inside wt (all mats stored as W^T [n][k])
#define WT_ENCW      0
#define WT_ENCWOUT   (4*16384)
#define WT_DECW      (5*16384)
#define WT_DECWOUT   (9*16384)
#define WT_COMB      (10*16384)  // (WencI@WdecI)^T [128][128]

// ws byte offsets
#define MFULL_OFF_B 0x60000      // f16 [50][128][128] (WencI@L^{s+1}@WdecI)^T
#define ACH_OFF_B   0x200000     // f32 [50][441]
#define PE_OFF_B    0x220000     // f16 LDS-image tiles [1632][16384B]
#define PET0_OFF_B  0x1C00000    // f16 [2048][128] compact pe at t=0 (chunk-linear)
#define CTRL_OFF_B  0x1D00000    // int ctrl[2]

// enc LDS buffers (16KB each): PA PB UA VA UB VB + bias(96K)
#define PA 0
#define PB 16384
#define UA 32768
#define VA 49152
#define UB 65536
#define VB 81920
#define LDSE (98304 + 2560 + 16)
// decpred LDS: dec: PP QQ UU VV XX YY ; pred: PP S0 A1 A2 S1 B1 B2 ; bias(112K)
#define PP 0
#define QQ 16384
#define UU 32768
#define VV 49152
#define XX 65536
#define YY 81920
#define ZZ 98304
#define LDSD (114688 + 2560 + 16)

#define hsw(rl, c) ((rl)*256 + ((((c)) ^ ((rl) & 7)) << 4))

// opaque pin: forbids rematerialization/sinking of weight loads into the loop
#define PIN(B) asm volatile("" : "+v"(B[0]), "+v"(B[1]), "+v"(B[2]), "+v"(B[3]), \
                                 "+v"(B[4]), "+v"(B[5]), "+v"(B[6]), "+v"(B[7]))

__device__ __forceinline__ f4 mfma16(h8 a, h8 b, f4 c) {
  return __builtin_amdgcn_mfma_f32_16x16x32_f16(a, b, c, 0, 0, 0);
}
__device__ __forceinline__ h8 cvt8(f4 a, f4 b) {
  h8 r;
  r[0]=(_Float16)a[0]; r[1]=(_Float16)a[1]; r[2]=(_Float16)a[2]; r[3]=(_Float16)a[3];
  r[4]=(_Float16)b[0]; r[5]=(_Float16)b[1]; r[6]=(_Float16)b[2]; r[7]=(_Float16)b[3];
  return r;
}
// wave's 32-col slice of a 128x128 W^T
__device__ __forceinline__ void loadW(h8 B[8], const _Float16* gW, int nbase, int r15, int hi) {
#pragma unroll
  for (int nt = 0; nt < 2; ++nt)
#pragma unroll
    for (int ks = 0; ks < 4; ++ks)
      B[nt*4+ks] = *(const h8*)(gW + (size_t)(nbase + nt*16 + r15)*128 + ks*32 + hi*8);
}

// SWAPPED operands, 32 rows at row-base rb: lane -> out[rb+rt*16+r15][wbase+nt*16+hi*4+d]
__device__ __forceinline__ void mm32(const char* sm, int hb, const h8 B[8],
                                     f4 acc[2][2], int rb, int r15, int hi) {
#pragma unroll
  for (int rt = 0; rt < 2; ++rt) { acc[rt][0] = (f4){0,0,0,0}; acc[rt][1] = (f4){0,0,0,0}; }
#pragma unroll
  for (int ks = 0; ks < 4; ++ks) {
    int c = ks*4 + hi;
    h8 a0 = *(const h8*)(sm + hb + hsw(rb + r15, c));
    h8 a1 = *(const h8*)(sm + hb + hsw(rb + 16 + r15, c));
    acc[0][0] = mfma16(B[ks],   a0, acc[0][0]);
    acc[0][1] = mfma16(B[4+ks], a0, acc[0][1]);
    acc[1][0] = mfma16(B[ks],   a1, acc[1][0]);
    acc[1][1] = mfma16(B[4+ks], a1, acc[1][1]);
  }
}

// ReLU(acc + bias) -> h[hb]
__device__ __forceinline__ void hw32s(char* sm, int hb, int rb, int wbase, const f4 acc[2][2],
                                      const float* bl, int bo, int r15, int hi) {
  f4 bb0 = *(const f4*)(bl + bo + wbase + hi*4);
  f4 bb1 = *(const f4*)(bl + bo + wbase + 16 + hi*4);
  int bo2 = (hi & 1) * 8;
#pragma unroll
  for (int nt = 0; nt < 2; ++nt) {
    int c = ((wbase + nt*16) >> 3) + (hi >> 1);
    f4 bb = nt ? bb1 : bb0;
#pragma unroll
    for (int rt = 0; rt < 2; ++rt) {
      int row = rb + rt*16 + r15;
      h4 p;
#pragma unroll
      for (int d = 0; d < 4; ++d) p[d] = (_Float16)fmaxf(acc[rt][nt][d] + bb[d], 0.f);
      *(h4*)(sm + hb + row*256 + ((c ^ (row & 7)) << 4) + bo2) = p;
    }
  }
}
// raw acc -> h[hb]
__device__ __forceinline__ void hw32r(char* sm, int hb, int rb, int wbase, const f4 acc[2][2],
                                      int r15, int hi) {
  int bo2 = (hi & 1) * 8;
#pragma unroll
  for (int nt = 0; nt < 2; ++nt) {
    int c = ((wbase + nt*16) >> 3) + (hi >> 1);
#pragma unroll
    for (int rt = 0; rt < 2; ++rt) {
      int row = rb + rt*16 + r15;
      h4 p;
#pragma unroll
      for (int d = 0; d < 4; ++d) p[d] = (_Float16)acc[rt][nt][d];
      *(h4*)(sm + hb + row*256 + ((c ^ (row & 7)) << 4) + bo2) = p;
    }
  }
}

// DIRECT epilogue: out = acc + bout(bl+512) + skip(LDS) -> f4 global, full sectors
__device__ __forceinline__ void epi32(const char* sm, int hskip, int rb, int wbase,
                                      const f4 acc[2][2], const float* bl,
                                      float* dst, int rstride, int r15, int hi) {
  f4 bb0 = *(const f4*)(bl + 512 + wbase + hi*4);
  f4 bb1 = *(const f4*)(bl + 512 + wbase + 16 + hi*4);
  int bo2 = (hi & 1) * 8;
#pragma unroll
  for (int nt = 0; nt < 2; ++nt) {
    int c = ((wbase + nt*16) >> 3) + (hi >> 1);
    int n0 = wbase + nt*16 + hi*4;
    f4 bb = nt ? bb1 : bb0;
#pragma unroll
    for (int rt = 0; rt < 2; ++rt) {
      int row = rb + rt*16 + r15;
      h4 sk = *(const h4*)(sm + hskip + row*256 + ((c ^ (row & 7)) << 4) + bo2);
      f4 v;
#pragma unroll
      for (int d = 0; d < 4; ++d) v[d] = acc[rt][nt][d] + bb[d] + (float)sk[d];
      *(f4*)(dst + (size_t)row*rstride + n0) = v;
    }
  }
}

#define TICKET(CTR, LIM, VAR)                                        \
    __syncthreads();                                                 \
    if (tid == 0) *tk = __hip_atomic_fetch_add(&(CTR), 1,            \
                          __ATOMIC_RELAXED, __HIP_MEMORY_SCOPE_AGENT); \
    __syncthreads();                                                 \
    int VAR = *tk;                                                   \
    if (VAR >= (LIM)) break;

// ---------------- prep kernels ----------------

__global__ __launch_bounds__(512) void k_prep(
    const float* __restrict__ encW, const float* __restrict__ encWout,
    const float* __restrict__ decW, const float* __restrict__ decWout,
    const float* __restrict__ L,
    _Float16* __restrict__ wt, float* __restrict__ ach) {
  __shared__ float chA[441], chB[441];
  int m = blockIdx.y, tid = threadIdx.x;
  if (m == 10) {
    if (blockIdx.x != 0) return;
    if (tid < 441) chA[tid] = L[tid];
    __syncthreads();
    for (int s = 0; s < 50; ++s) {
      if (tid < 441) ach[s*441 + tid] = chA[tid];
      if (s == 49) break;
      if (tid < 441) {
        int i = tid / 21, j = tid % 21; float a = 0.f;
        for (int k = 0; k < 21; ++k) a += chA[i*21 + k] * L[k*21 + j];
        chB[tid] = a;
      }
      __syncthreads();
      if (tid < 441) chA[tid] = chB[tid];
      __syncthreads();
    }
    return;
  }
  int idx = blockIdx.x*512 + tid;
  if (idx >= 16384) return;
  const float* src; _Float16* dst;
  if (m < 4)       { src = encW + m*16384;     dst = wt + WT_ENCW + m*16384; }
  else if (m == 4) { src = encWout;            dst = wt + WT_ENCWOUT; }
  else if (m < 9)  { src = decW + (m-5)*16384; dst = wt + WT_DECW + (m-5)*16384; }
  else             { src = decWout;            dst = wt + WT_DECWOUT; }
  int n = idx >> 7, k = idx & 127;
  dst[idx] = (_Float16)src[k*128 + n];            // W^T[n][k]
}

__global__ __launch_bounds__(512) void k_aux(
    const float* __restrict__ ach, const float* __restrict__ wencI,
    const float* __restrict__ wdecI,
    _Float16* __restrict__ mfull, _Float16* __restrict__ wt) {
  __shared__ float T1[2688];
  __shared__ float sa[441];
  int s = blockIdx.x, t = threadIdx.x;
  if (s < 50) {
    if (t < 441) sa[t] = ach[s*441 + t];
    __syncthreads();
    for (int idx = t; idx < 2688; idx += 512) {
      int k = idx / 21, j = idx % 21;
      float a = 0.f;
      for (int u = 0; u < 21; ++u) a += wencI[k*21 + u] * sa[u*21 + j];
      T1[idx] = a;
    }
  } else {
    for (int idx = t; idx < 2688; idx += 512) T1[idx] = wencI[idx];
  }
  __syncthreads();
  _Float16* dst = (s < 50) ? (mfull + (size_t)s*16384) : (wt + WT_COMB);
  for (int idx = t; idx < 16384; idx += 512) {    // M^T[n][k]
    int n = idx >> 7, k = idx & 127;
    float a = 0.f;
    for (int j = 0; j < 21; ++j) a += T1[k*21 + j] * wdecI[j*128 + n];
    dst[idx] = (_Float16)a;
  }
}

// ---------------- encoder: tile PAIRS, dual-stream ----------------

__global__ __launch_bounds__(512, 2) void k_enc(
    const float* __restrict__ x, const _Float16* __restrict__ wt,
    const float* __restrict__ enc_b, const float* __restrict__ enc_bout,
    _Float16* __restrict__ pe_ws, _Float16* __restrict__ pet0,
    int* __restrict__ ctrl) {
  __shared__ char sm[LDSE];
  float* bl = (float*)(sm + 98304);
  int* tk = (int*)(sm + 98304 + 2560);
  int tid = threadIdx.x, lane = tid & 63, w = tid >> 6;
  int r15 = lane & 15, hi = lane >> 4;
  int rb = (w >> 2) * 32, wbase = (w & 3) * 32;
  h8 B0[8], B1[8], B2[8], B3[8], B4[8];
  loadW(B0, wt + WT_ENCW,           wbase, r15, hi);
  loadW(B1, wt + WT_ENCW + 16384,   wbase, r15, hi);
  loadW(B2, wt + WT_ENCW + 2*16384, wbase, r15, hi);
  loadW(B3, wt + WT_ENCW + 3*16384, wbase, r15, hi);
  loadW(B4, wt + WT_ENCWOUT,        wbase, r15, hi);
  PIN(B0); PIN(B1); PIN(B2); PIN(B3); PIN(B4);
  if (tid < 512) bl[tid] = enc_b[tid];
  if (tid < 128) bl[512 + tid] = enc_bout[tid];
  f4 aA[2][2], aB[2][2];

  for (;;) {
    TICKET(ctrl[0], NPAIR, v);
    int tA = v*2, tB = v*2 + 1;
    size_t rbA = (size_t)tA * 64, rbB = (size_t)tB * 64;
#pragma unroll
    for (int i = 0; i < 2; ++i) {                 // stage xA -> PA, xB -> PB
      int idx = i*512 + tid, rl = idx >> 4, c = idx & 15;
      const float* sA = x + (rbA + rl)*128 + c*8;
      const float* sB = x + (rbB + rl)*128 + c*8;
      *(h8*)(sm + PA + hsw(rl, c)) = cvt8(*(const f4*)sA, *(const f4*)(sA + 4));
      *(h8*)(sm + PB + hsw(rl, c)) = cvt8(*(const f4*)sB, *(const f4*)(sB + 4));
    }
    __syncthreads();
    // L0..L3, dual stream
    mm32(sm, PA, B0, aA, rb, r15, hi); hw32s(sm, UA, rb, wbase, aA, bl, 0, r15, hi);
    mm32(sm, PB, B0, aB, rb, r15, hi); hw32s(sm, UB, rb, wbase, aB, bl, 0, r15, hi);
    __syncthreads();
    mm32(sm, UA, B1, aA, rb, r15, hi); hw32s(sm, VA, rb, wbase, aA, bl, 128, r15, hi);
    mm32(sm, UB, B1, aB, rb, r15, hi); hw32s(sm, VB, rb, wbase, aB, bl, 128, r15, hi);
    __syncthreads();
    mm32(sm, VA, B2, aA, rb, r15, hi); hw32s(sm, UA, rb, wbase, aA, bl, 256, r15, hi);
    mm32(sm, VB, B2, aB, rb, r15, hi); hw32s(sm, UB, rb, wbase, aB, bl, 256, r15, hi);
    __syncthreads();
    mm32(sm, UA, B3, aA, rb, r15, hi); hw32s(sm, VA, rb, wbase, aA, bl, 384, r15, hi);
    mm32(sm, UB, B3, aB, rb, r15, hi); hw32s(sm, VB, rb, wbase, aB, bl, 384, r15, hi);
    __syncthreads();
    mm32(sm, VA, B4, aA, rb, r15, hi);            // encWout both
    mm32(sm, VB, B4, aB, rb, r15, hi);
    {                                             // pe = acc + bout + x, in-place PA/PB
      f4 bb0 = *(const f4*)(bl + 512 + wbase + hi*4);
      f4 bb1 = *(const f4*)(bl + 512 + wbase + 16 + hi*4);
      int bo2 = (hi & 1) * 8;
#pragma unroll
      for (int nt = 0; nt < 2; ++nt) {
        int c = ((wbase + nt*16) >> 3) + (hi >> 1);
        f4 bb = nt ? bb1 : bb0;
#pragma unroll
        for (int rt = 0; rt < 2; ++rt) {
          int row = rb + rt*16 + r15;
          int so = row*256 + ((c ^ (row & 7)) << 4) + bo2;
          h4 skA = *(const h4*)(sm + PA + so);
          h4 skB = *(const h4*)(sm + PB + so);
          h4 pA_, pB_;
#pragma unroll
          for (int d = 0; d < 4; ++d) {
            pA_[d] = (_Float16)(aA[rt][nt][d] + bb[d] + (float)skA[d]);
            pB_[d] = (_Float16)(aB[rt][nt][d] + bb[d] + (float)skB[d]);
          }
          *(h4*)(sm + PA + so) = pA_;             // lane-private slots
          *(h4*)(sm + PB + so) = pB_;
        }
      }
    }
    __syncthreads();
    {                                             // dump pe images + pet0
      char* gA = (char*)pe_ws + (size_t)tA*16384;
      char* gB = (char*)pe_ws + (size_t)tB*16384;
#pragma unroll
      for (int i = 0; i < 2; ++i) {
        int idx = i*512 + tid, off = idx*16;
        f4 vA = *(const f4*)(sm + PA + off);
        f4 vB = *(const f4*)(sm + PB + off);
        *(f4*)(gA + off) = vA;
        *(f4*)(gB + off) = vB;
        int rl = idx >> 4, slot = idx & 15;
        int c = slot ^ (rl & 7);                  // unswizzle -> chunk-linear
        size_t rgA = rbA + (size_t)rl;
        size_t rgB = rbB + (size_t)rl;
        if (rgA % 51u == 0u) *(f4*)((char*)pet0 + (rgA/51u)*256 + c*16) = vA;
        if (rgB % 51u == 0u) *(f4*)((char*)pet0 + (rgB/51u)*256 + c*16) = vB;
      }
    }
  }
}

// ---------------- dec tiles + pred units, dual-stream ----------------

__global__ __launch_bounds__(512, 2) void k_decpred(
    const _Float16* __restrict__ wt, const _Float16* __restrict__ pe_ws,
    const _Float16* __restrict__ pet0, const _Float16* __restrict__ mfull,
    const float* __restrict__ dec_b, const float* __restrict__ dec_bout,
    float* __restrict__ out1, float* __restrict__ out2, float* __restrict__ out3,
    int* __restrict__ ctrl) {
  __shared__ char sm[LDSD];
  float* bl = (float*)(sm + 114688);
  int* tk = (int*)(sm + 114688 + 2560);
  int tid = threadIdx.x, lane = tid & 63, w = tid >> 6;
  int r15 = lane & 15, hi = lane >> 4;
  int rb = (w >> 2) * 32, wbase = (w & 3) * 32;
  h8 B0[8], B1[8], B2[8], B3[8], B4[8];
  loadW(B0, wt + WT_DECW,           wbase, r15, hi);
  loadW(B1, wt + WT_DECW + 16384,   wbase, r15, hi);
  loadW(B2, wt + WT_DECW + 2*16384, wbase, r15, hi);
  loadW(B3, wt + WT_DECW + 3*16384, wbase, r15, hi);
  loadW(B4, wt + WT_DECWOUT,        wbase, r15, hi);
  PIN(B0); PIN(B1); PIN(B2); PIN(B3); PIN(B4);
  if (tid < 512) bl[tid] = dec_b[tid];
  if (tid < 128) bl[512 + tid] = dec_bout[tid];
  f4 aB_[2][2], aA_[2][2];                        // stream B (pe/step0), stream A (pd/step1)

  for (;;) {
    TICKET(ctrl[1], NUNITS, u);
    if (u < NT64) {
      // ----- dec tile: B = dec(pe) -> out2 ; A = dec(pd=pe@comb) -> out1 -----
      const char* src = (const char*)pe_ws + (size_t)u*16384;
#pragma unroll
      for (int i = 0; i < 2; ++i) {               // stage pe -> PP
        int off = (i*512 + tid)*16;
        *(f4*)(sm + PP + off) = *(const f4*)(src + off);
      }
      __syncthreads();
      {                                           // pd = pe@comb ; B-L0
        h8 Bc[8];
        loadW(Bc, wt + WT_COMB, wbase, r15, hi);
        mm32(sm, PP, Bc, aA_, rb, r15, hi);
      }
      hw32r(sm, QQ, rb, wbase, aA_, r15, hi);
      mm32(sm, PP, B0, aB_, rb, r15, hi); hw32s(sm, UU, rb, wbase, aB_, bl, 0, r15, hi);
      __syncthreads();
      mm32(sm, UU, B1, aB_, rb, r15, hi); hw32s(sm, VV, rb, wbase, aB_, bl, 128, r15, hi);
      mm32(sm, QQ, B0, aA_, rb, r15, hi); hw32s(sm, XX, rb, wbase, aA_, bl, 0,   r15, hi);
      __syncthreads();
      mm32(sm, VV, B2, aB_, rb, r15, hi); hw32s(sm, UU, rb, wbase, aB_, bl, 256, r15, hi);
      mm32(sm, XX, B1, aA_, rb, r15, hi); hw32s(sm, YY, rb, wbase, aA_, bl, 128, r15, hi);
      __syncthreads();
      mm32(sm, UU, B3, aB_, rb, r15, hi); hw32s(sm, VV, rb, wbase, aB_, bl, 384, r15, hi);
      mm32(sm, YY, B2, aA_, rb, r15, hi); hw32s(sm, XX, rb, wbase, aA_, bl, 256, r15, hi);
      __syncthreads();
      mm32(sm, VV, B4, aB_, rb, r15, hi);         // B Wout
      epi32(sm, PP, rb, wbase, aB_, bl, out2 + (size_t)u*64*128, 128, r15, hi);
      mm32(sm, XX, B3, aA_, rb, r15, hi); hw32s(sm, YY, rb, wbase, aA_, bl, 384, r15, hi);
      __syncthreads();
      mm32(sm, YY, B4, aA_, rb, r15, hi);         // A Wout
      epi32(sm, QQ, rb, wbase, aA_, bl, out1 + (size_t)u*64*128, 128, r15, hi);
    } else {
      // ----- pred unit: steps s0 (stream B) and s0+1 (stream A) -----
      int p = u - NT64, rtile = p / 25, s0 = (p % 25) * 2;
#pragma unroll
      for (int i = 0; i < 2; ++i) {               // stage pet0 -> PP
        int idx = i*512 + tid, rl = idx >> 4, c = idx & 15;
        f4 v = *(const f4*)((const char*)pet0 + (size_t)(rtile*64 + rl)*256 + c*16);
        *(f4*)(sm + PP + hsw(rl, c)) = v;
      }
      __syncthreads();
      {                                           // di0 = pet0 @ Mfull_s0 -> QQ
        h8 Bm[8];
        loadW(Bm, mfull + (size_t)s0*16384, wbase, r15, hi);
        mm32(sm, PP, Bm, aB_, rb, r15, hi);
      }
      hw32r(sm, QQ, rb, wbase, aB_, r15, hi);
      {                                           // di1 = pet0 @ Mfull_s0+1 -> XX
        h8 Bm[8];
        loadW(Bm, mfull + (size_t)(s0+1)*16384, wbase, r15, hi);
        mm32(sm, PP, Bm, aA_, rb, r15, hi);
      }
      hw32r(sm, XX, rb, wbase, aA_, r15, hi);
      __syncthreads();
      mm32(sm, QQ, B0, aB_, rb, r15, hi); hw32s(sm, UU, rb, wbase, aB_, bl, 0, r15, hi);
      mm32(sm, XX, B0, aA_, rb, r15, hi); hw32s(sm, YY, rb, wbase, aA_, bl, 0, r15, hi);
      __syncthreads();
      mm32(sm, UU, B1, aB_, rb, r15, hi); hw32s(sm, VV, rb, wbase, aB_, bl, 128, r15, hi);
      mm32(sm, YY, B1, aA_, rb, r15, hi); hw32s(sm, ZZ, rb, wbase, aA_, bl, 128, r15, hi);
      __syncthreads();
      mm32(sm, VV, B2, aB_, rb, r15, hi); hw32s(sm, UU, rb, wbase, aB_, bl, 256, r15, hi);
      mm32(sm, ZZ, B2, aA_, rb, r15, hi); hw32s(sm, YY, rb, wbase, aA_, bl, 256, r15, hi);
      __syncthreads();
      mm32(sm, UU, B3, aB_, rb, r15, hi); hw32s(sm, VV, rb, wbase, aB_, bl, 384, r15, hi);
      mm32(sm, YY, B3, aA_, rb, r15, hi); hw32s(sm, ZZ, rb, wbase, aA_, bl, 384, r15, hi);
      __syncthreads();
      float* d3 = out3 + (size_t)rtile*64*50*128;
      mm32(sm, VV, B4, aB_, rb, r15, hi);
      epi32(sm, QQ, rb, wbase, aB_, bl, d3 + (size_t)s0*128, 50*128, r15, hi);
      mm32(sm, ZZ, B4, aA_, rb, r15, hi);
      epi32(sm, XX, rb, wbase, aA_, bl, d3 + (size_t)(s0+1)*128, 50*128, r15, hi);
    }
  }
}

// ---------------- launch ----------------

extern "C" void kernel_launch(void* const* d_in, const int* in_sizes, int n_in,
                              void* d_out, int out_size, void* d_ws, size_t ws_size,
                              hipStream_t stream) {
  const float* x        = (const float*)d_in[0];
  const float* encW     = (const float*)d_in[1];
  const float* enc_b    = (const float*)d_in[2];
  const float* encWout  = (const float*)d_in[3];
  const float* enc_bout = (const float*)d_in[4];
  const float* decW     = (const float*)d_in[5];
  const float* dec_b    = (const float*)d_in[6];
  const float* decWout  = (const float*)d_in[7];
  const float* dec_bout = (const float*)d_in[8];
  const float* wencI    = (const float*)d_in[9];
  const float* L        = (const float*)d_in[10];
  const float* wdecI    = (const float*)d_in[11];

  char* ws = (char*)d_ws;
  _Float16* wt    = (_Float16*)ws;
  _Float16* mfull = (_Float16*)(ws + MFULL_OFF_B);
  float*    ach   = (float*)(ws + ACH_OFF_B);
  _Float16* pe_ws = (_Float16*)(ws + PE_OFF_B);
  _Float16* pet0  = (_Float16*)(ws + PET0_OFF_B);
  int*      ctrl  = (int*)(ws + CTRL_OFF_B);

  float* out1 = (float*)d_out;                       // autoencoder_output
  float* out2 = out1 + (size_t)ROWS_AUTO*128;        // outer_auto_output
  float* out3 = out2 + (size_t)ROWS_AUTO*128;        // predictions [2048][50][128]

  hipMemsetAsync(ctrl, 0, sizeof(int)*2, stream);
  hipLaunchKernelGGL(k_prep, dim3(32, 11), dim3(512), 0, stream,
                     encW, encWout, decW, decWout, L, wt, ach);
  hipLaunchKernelGGL(k_aux, dim3(51), dim3(512), 0, stream,
                     ach, wencI, wdecI, mfull, wt);
  hipLaunchKernelGGL(k_enc, dim3(256), dim3(512), 0, stream,
                     x, wt, enc_b, enc_bout, pe_ws, pet0, ctrl);
  hipLaunchKernelGGL(k_decpred, dim3(256), dim3(512), 0, stream,
                     wt, pe_ws, pet0, mfull, dec_b, dec_bout, out1, out2, out3, ctrl);
}

// Round 18
// 227.212 us; speedup vs baseline: 1.0271x; 1.0271x over previous
//
#include <hip/hip_runtime.h>
#include <stdint.h>

// Koopman autoencoder — round 18 (MI355X / gfx950).
// R14 base (pinned weights, direct f4 stores, 2 blocks/CU) +
// (1) s_setprio around MFMA clusters (2 blocks/CU at different phases),
// (2) cross-tile pe prefetch in k_decpred, (3) cross-tile x prefetch in k_enc.

typedef _Float16 h8 __attribute__((ext_vector_type(8)));
typedef _Float16 h4 __attribute__((ext_vector_type(4)));
typedef float    f4 __attribute__((ext_vector_type(4)));

#define ROWS_AUTO 104448
#define NT64      1632           // 64-row dec tiles
#define NUNITS    2432           // 1632 dec + 800 pred (32 rtiles x 25 chunks x 2 steps)

// half-element offsets inside wt (all mats stored as W^T [n][k])
#define WT_ENCW      0
#define WT_ENCWOUT   (4*16384)
#define WT_DECW      (5*16384)
#define WT_DECWOUT   (9*16384)
#define WT_COMB      (10*16384)  // (WencI@WdecI)^T [128][128]

// ws byte offsets
#define MFULL_OFF_B 0x60000      // f16 [50][128][128] (WencI@L^{s+1}@WdecI)^T
#define ACH_OFF_B   0x200000     // f32 [50][441]
#define PE_OFF_B    0x220000     // f16 LDS-image tiles [1632][16384B]
#define PET0_OFF_B  0x1C00000    // f16 [2048][128] compact pe at t=0 (chunk-linear)

// LDS buffers (16KB each)
#define H0 0
#define H1 16384
#define H2 32768
#define H3 49152
#define LDSE (49152 + 2560)      // k_enc: H0..H2 + 640 f32 biases
#define LDSD (65536 + 2560)      // k_decpred: H0..H3 + 640 f32 biases

#define hsw(rl, c) ((rl)*256 + ((((c)) ^ ((rl) & 7)) << 4))

// opaque pin: forbids rematerialization/sinking of weight loads into the loop
#define PIN(B) asm volatile("" : "+v"(B[0]), "+v"(B[1]), "+v"(B[2]), "+v"(B[3]), \
                                 "+v"(B[4]), "+v"(B[5]), "+v"(B[6]), "+v"(B[7]))

__device__ __forceinline__ f4 mfma16(h8 a, h8 b, f4 c) {
  return __builtin_amdgcn_mfma_f32_16x16x32_f16(a, b, c, 0, 0, 0);
}
__device__ __forceinline__ h8 cvt8(f4 a, f4 b) {
  h8 r;
  r[0]=(_Float16)a[0]; r[1]=(_Float16)a[1]; r[2]=(_Float16)a[2]; r[3]=(_Float16)a[3];
  r[4]=(_Float16)b[0]; r[5]=(_Float16)b[1]; r[6]=(_Float16)b[2]; r[7]=(_Float16)b[3];
  return r;
}
// wave's 32-col slice of a 128x128 W^T
__device__ __forceinline__ void loadW(h8 B[8], const _Float16* gW, int nbase, int r15, int hi) {
#pragma unroll
  for (int nt = 0; nt < 2; ++nt)
#pragma unroll
    for (int ks = 0; ks < 4; ++ks)
      B[nt*4+ks] = *(const h8*)(gW + (size_t)(nbase + nt*16 + r15)*128 + ks*32 + hi*8);
}

// SWAPPED operands: lane holds out[row=rt*16+r15][n=wbase+nt*16+hi*4+d]
// setprio(1) around the MFMA cluster (T5: 2 blocks/CU at different phases).
__device__ __forceinline__ void mmF4s(const char* sm, int hb, const h8 B[8],
                                      f4 acc[4][2], int r15, int hi) {
#pragma unroll
  for (int rt = 0; rt < 4; ++rt) { acc[rt][0] = (f4){0,0,0,0}; acc[rt][1] = (f4){0,0,0,0}; }
  __builtin_amdgcn_s_setprio(1);
#pragma unroll
  for (int ks = 0; ks < 4; ++ks) {
    int c = ks*4 + hi;
    h8 a[4];
#pragma unroll
    for (int rt = 0; rt < 4; ++rt) a[rt] = *(const h8*)(sm + hb + hsw(rt*16 + r15, c));
#pragma unroll
    for (int rt = 0; rt < 4; ++rt) {
      acc[rt][0] = mfma16(B[ks],   a[rt], acc[rt][0]);
      acc[rt][1] = mfma16(B[4+ks], a[rt], acc[rt][1]);
    }
  }
  __builtin_amdgcn_s_setprio(0);
}

// ReLU(acc + bias) -> h[hb] via b64 writes
__device__ __forceinline__ void hw4s(char* sm, int hb, int wbase, const f4 acc[4][2],
                                     const float* bl, int bo, int r15, int hi) {
  f4 bb0 = *(const f4*)(bl + bo + wbase + hi*4);
  f4 bb1 = *(const f4*)(bl + bo + wbase + 16 + hi*4);
  int bo2 = (hi & 1) * 8;
#pragma unroll
  for (int nt = 0; nt < 2; ++nt) {
    int c = ((wbase + nt*16) >> 3) + (hi >> 1);
    f4 bb = nt ? bb1 : bb0;
#pragma unroll
    for (int rt = 0; rt < 4; ++rt) {
      int row = rt*16 + r15;
      h4 p;
#pragma unroll
      for (int d = 0; d < 4; ++d) p[d] = (_Float16)fmaxf(acc[rt][nt][d] + bb[d], 0.f);
      *(h4*)(sm + hb + row*256 + ((c ^ (row & 7)) << 4) + bo2) = p;
    }
  }
}
// raw acc -> h[hb] (no bias/relu)
__device__ __forceinline__ void hw4r(char* sm, int hb, int wbase, const f4 acc[4][2],
                                     int r15, int hi) {
  int bo2 = (hi & 1) * 8;
#pragma unroll
  for (int nt = 0; nt < 2; ++nt) {
    int c = ((wbase + nt*16) >> 3) + (hi >> 1);
#pragma unroll
    for (int rt = 0; rt < 4; ++rt) {
      int row = rt*16 + r15;
      h4 p;
#pragma unroll
      for (int d = 0; d < 4; ++d) p[d] = (_Float16)acc[rt][nt][d];
      *(h4*)(sm + hb + row*256 + ((c ^ (row & 7)) << 4) + bo2) = p;
    }
  }
}

// DIRECT epilogue: out = acc + bout + skip(LDS) -> f4 global (full sectors, no barriers)
__device__ __forceinline__ void epi_direct(const char* sm, int hskip, int wbase,
                                           const f4 acc[4][2], const float* bl,
                                           float* dst, int rstride, int r15, int hi) {
  f4 bb0 = *(const f4*)(bl + 512 + wbase + hi*4);
  f4 bb1 = *(const f4*)(bl + 512 + wbase + 16 + hi*4);
  int bo2 = (hi & 1) * 8;
#pragma unroll
  for (int nt = 0; nt < 2; ++nt) {
    int c = ((wbase + nt*16) >> 3) + (hi >> 1);
    int n0 = wbase + nt*16 + hi*4;
    f4 bb = nt ? bb1 : bb0;
#pragma unroll
    for (int rt = 0; rt < 4; ++rt) {
      int row = rt*16 + r15;
      h4 sk = *(const h4*)(sm + hskip + row*256 + ((c ^ (row & 7)) << 4) + bo2);
      f4 v;
#pragma unroll
      for (int d = 0; d < 4; ++d) v[d] = acc[rt][nt][d] + bb[d] + (float)sk[d];
      *(f4*)(dst + (size_t)row*rstride + n0) = v;
    }
  }
}

#define LAYD(HIN, HOUT, BW, BO) do {                                 \
    mmF4s(sm, HIN, BW, acc, r15, hi);                                \
    hw4s(sm, HOUT, wbase, acc, bl, BO, r15, hi);                     \
    __syncthreads();                                                 \
  } while (0)

// ---------------- prep kernels ----------------

__global__ __launch_bounds__(512) void k_prep(
    const float* __restrict__ encW, const float* __restrict__ encWout,
    const float* __restrict__ decW, const float* __restrict__ decWout,
    const float* __restrict__ L,
    _Float16* __restrict__ wt, float* __restrict__ ach) {
  __shared__ float chA[441], chB[441];
  int m = blockIdx.y, tid = threadIdx.x;
  if (m == 10) {
    if (blockIdx.x != 0) return;
    if (tid < 441) chA[tid] = L[tid];
    __syncthreads();
    for (int s = 0; s < 50; ++s) {
      if (tid < 441) ach[s*441 + tid] = chA[tid];
      if (s == 49) break;
      if (tid < 441) {
        int i = tid / 21, j = tid % 21; float a = 0.f;
        for (int k = 0; k < 21; ++k) a += chA[i*21 + k] * L[k*21 + j];
        chB[tid] = a;
      }
      __syncthreads();
      if (tid < 441) chA[tid] = chB[tid];
      __syncthreads();
    }
    return;
  }
  int idx = blockIdx.x*512 + tid;
  if (idx >= 16384) return;
  const float* src; _Float16* dst;
  if (m < 4)       { src = encW + m*16384;     dst = wt + WT_ENCW + m*16384; }
  else if (m == 4) { src = encWout;            dst = wt + WT_ENCWOUT; }
  else if (m < 9)  { src = decW + (m-5)*16384; dst = wt + WT_DECW + (m-5)*16384; }
  else             { src = decWout;            dst = wt + WT_DECWOUT; }
  int n = idx >> 7, k = idx & 127;
  dst[idx] = (_Float16)src[k*128 + n];            // W^T[n][k]
}

__global__ __launch_bounds__(512) void k_aux(
    const float* __restrict__ ach, const float* __restrict__ wencI,
    const float* __restrict__ wdecI,
    _Float16* __restrict__ mfull, _Float16* __restrict__ wt) {
  __shared__ float T1[2688];
  __shared__ float sa[441];
  int s = blockIdx.x, t = threadIdx.x;
  if (s < 50) {
    if (t < 441) sa[t] = ach[s*441 + t];
    __syncthreads();
    for (int idx = t; idx < 2688; idx += 512) {
      int k = idx / 21, j = idx % 21;
      float a = 0.f;
      for (int u = 0; u < 21; ++u) a += wencI[k*21 + u] * sa[u*21 + j];
      T1[idx] = a;
    }
  } else {
    for (int idx = t; idx < 2688; idx += 512) T1[idx] = wencI[idx];
  }
  __syncthreads();
  _Float16* dst = (s < 50) ? (mfull + (size_t)s*16384) : (wt + WT_COMB);
  for (int idx = t; idx < 16384; idx += 512) {    // M^T[n][k]
    int n = idx >> 7, k = idx & 127;
    float a = 0.f;
    for (int j = 0; j < 21; ++j) a += T1[k*21 + j] * wdecI[j*128 + n];
    dst[idx] = (_Float16)a;
  }
}

// ---------------- encoder: x -> pe image + compact pet0 ----------------

__global__ __launch_bounds__(256, 2) void k_enc(
    const float* __restrict__ x, const _Float16* __restrict__ wt,
    const float* __restrict__ enc_b, const float* __restrict__ enc_bout,
    _Float16* __restrict__ pe_ws, _Float16* __restrict__ pet0) {
  __shared__ char sm[LDSE];
  float* bl = (float*)(sm + 49152);
  int tid = threadIdx.x, lane = tid & 63;
  int r15 = lane & 15, hi = lane >> 4;
  int wbase = (tid >> 6) * 32;
  h8 B0[8], B1[8], B2[8], B3[8], B4[8];
  loadW(B0, wt + WT_ENCW,           wbase, r15, hi);
  loadW(B1, wt + WT_ENCW + 16384,   wbase, r15, hi);
  loadW(B2, wt + WT_ENCW + 2*16384, wbase, r15, hi);
  loadW(B3, wt + WT_ENCW + 3*16384, wbase, r15, hi);
  loadW(B4, wt + WT_ENCWOUT,        wbase, r15, hi);
  PIN(B0); PIN(B1); PIN(B2); PIN(B3); PIN(B4);
  bl[tid] = enc_b[tid]; bl[256 + tid] = enc_b[256 + tid];
  if (tid < 128) bl[512 + tid] = enc_bout[tid];
  f4 acc[4][2];
  f4 pfx[8];
  bool pfv = false;

  for (int t = blockIdx.x; t < NT64; t += gridDim.x) {
    size_t rb = (size_t)t * 64;
    if (pfv) {
#pragma unroll
      for (int i = 0; i < 4; ++i) {               // stage prefetched x -> H0
        int idx = i*256 + tid, rl = idx >> 4, c = idx & 15;
        *(h8*)(sm + H0 + hsw(rl, c)) = cvt8(pfx[2*i], pfx[2*i+1]);
      }
    } else {
#pragma unroll
      for (int i = 0; i < 4; ++i) {               // stage x -> H0 (enc skip)
        int idx = i*256 + tid, rl = idx >> 4, c = idx & 15;
        const float* s = x + (rb + rl)*128 + c*8;
        f4 v0 = *(const f4*)s, v1 = *(const f4*)(s + 4);
        *(h8*)(sm + H0 + hsw(rl, c)) = cvt8(v0, v1);
      }
    }
    __syncthreads();
    LAYD(H0, H1, B0, 0); LAYD(H1, H2, B1, 128);
    LAYD(H2, H1, B2, 256); LAYD(H1, H2, B3, 384);
    mmF4s(sm, H2, B4, acc, r15, hi);              // encWout
    {                                             // prefetch next tile's x
      int tn = t + (int)gridDim.x;
      pfv = (tn < NT64);
      if (pfv) {
#pragma unroll
        for (int i = 0; i < 4; ++i) {
          int idx = i*256 + tid, rl = idx >> 4, c = idx & 15;
          const float* s = x + ((size_t)tn*64 + rl)*128 + c*8;
          pfx[2*i] = *(const f4*)s; pfx[2*i+1] = *(const f4*)(s + 4);
        }
      }
    }
    {                                             // pe = acc + bout + x, in-place H0
      f4 bb0 = *(const f4*)(bl + 512 + wbase + hi*4);
      f4 bb1 = *(const f4*)(bl + 512 + wbase + 16 + hi*4);
      int bo2 = (hi & 1) * 8;
#pragma unroll
      for (int nt = 0; nt < 2; ++nt) {
        int c = ((wbase + nt*16) >> 3) + (hi >> 1);
        f4 bb = nt ? bb1 : bb0;
#pragma unroll
        for (int rt = 0; rt < 4; ++rt) {
          int row = rt*16 + r15;
          int soff = H0 + row*256 + ((c ^ (row & 7)) << 4) + bo2;
          h4 sk = *(const h4*)(sm + soff);
          h4 p;
#pragma unroll
          for (int d = 0; d < 4; ++d) p[d] = (_Float16)(acc[rt][nt][d] + bb[d] + (float)sk[d]);
          *(h4*)(sm + soff) = p;                  // lane-private slot: no race
        }
      }
    }
    __syncthreads();
    {                                             // dump pe image + compact pet0
      char* g = (char*)(pe_ws) + (size_t)t*16384;
#pragma unroll
      for (int i = 0; i < 4; ++i) {
        int idx = i*256 + tid, off = idx*16;
        f4 v = *(const f4*)(sm + H0 + off);
        *(f4*)(g + off) = v;
        int rl = idx >> 4, slot = idx & 15;
        size_t rg = rb + (size_t)rl;
        if (rg % 51u == 0u) {
          int c = slot ^ (rl & 7);                // unswizzle -> chunk-linear
          *(f4*)((char*)pet0 + (rg/51u)*256 + c*16) = v;
        }
      }
    }
    __syncthreads();                              // dump reads done before next tile
  }
}

// ---------------- dec tiles + pred units (direct-store epilogues) ----------------

__global__ __launch_bounds__(256, 2) void k_decpred(
    const _Float16* __restrict__ wt, const _Float16* __restrict__ pe_ws,
    const _Float16* __restrict__ pet0, const _Float16* __restrict__ mfull,
    const float* __restrict__ dec_b, const float* __restrict__ dec_bout,
    float* __restrict__ out1, float* __restrict__ out2, float* __restrict__ out3) {
  __shared__ char sm[LDSD];
  float* bl = (float*)(sm + 65536);
  int tid = threadIdx.x, lane = tid & 63;
  int r15 = lane & 15, hi = lane >> 4;
  int wbase = (tid >> 6) * 32;
  h8 B0[8], B1[8], B2[8], B3[8], B4[8];
  loadW(B0, wt + WT_DECW,           wbase, r15, hi);
  loadW(B1, wt + WT_DECW + 16384,   wbase, r15, hi);
  loadW(B2, wt + WT_DECW + 2*16384, wbase, r15, hi);
  loadW(B3, wt + WT_DECW + 3*16384, wbase, r15, hi);
  loadW(B4, wt + WT_DECWOUT,        wbase, r15, hi);
  PIN(B0); PIN(B1); PIN(B2); PIN(B3); PIN(B4);
  bl[tid] = dec_b[tid]; bl[256 + tid] = dec_b[256 + tid];
  if (tid < 128) bl[512 + tid] = dec_bout[tid];
  f4 acc[4][2];
  f4 pf[4];
  bool pfv = false;

  for (int u = blockIdx.x; u < NUNITS; u += gridDim.x) {
    __syncthreads();                              // protect h bufs across units
    if (u < NT64) {
      // ---------- dec tile: pe -> out2 ; pd = pe@comb -> dec -> out1 ----------
      if (pfv) {
#pragma unroll
        for (int i = 0; i < 4; ++i)               // stage prefetched pe -> H0
          *(f4*)(sm + H0 + (i*256 + tid)*16) = pf[i];
      } else {
        const char* src = (const char*)pe_ws + (size_t)u*16384;
#pragma unroll
        for (int i = 0; i < 4; ++i) {             // stage pe -> H0 (input+skip)
          int off = (i*256 + tid)*16;
          *(f4*)(sm + H0 + off) = *(const f4*)(src + off);
        }
      }
      __syncthreads();
      {                                           // prefetch next dec tile's pe
        int un = u + (int)gridDim.x;
        pfv = (un < NT64);
        if (pfv) {
          const char* s2 = (const char*)pe_ws + (size_t)un*16384;
#pragma unroll
          for (int i = 0; i < 4; ++i) pf[i] = *(const f4*)(s2 + (i*256 + tid)*16);
        }
      }
      LAYD(H0, H1, B0, 0); LAYD(H1, H2, B1, 128);
      LAYD(H2, H1, B2, 256); LAYD(H1, H2, B3, 384);
      mmF4s(sm, H2, B4, acc, r15, hi);            // decWout
      epi_direct(sm, H0, wbase, acc, bl,
                 out2 + (size_t)u*64*128, 128, r15, hi);
      {                                           // pd = pe @ comb (transient regs)
        h8 Bc[8];
        loadW(Bc, wt + WT_COMB, wbase, r15, hi);
        mmF4s(sm, H0, Bc, acc, r15, hi);
      }
      hw4r(sm, H3, wbase, acc, r15, hi);          // pd -> H3 (input+skip)
      __syncthreads();
      LAYD(H3, H0, B0, 0); LAYD(H0, H1, B1, 128);
      LAYD(H1, H0, B2, 256); LAYD(H0, H1, B3, 384);
      mmF4s(sm, H1, B4, acc, r15, hi);            // decWout
      epi_direct(sm, H3, wbase, acc, bl,
                 out1 + (size_t)u*64*128, 128, r15, hi);
    } else {
      // ---------- pred unit: pet0 rtile x 2 Koopman steps ----------
      pfv = false;
      int p = u - NT64, rtile = p / 25, chunk = p % 25;
#pragma unroll
      for (int i = 0; i < 4; ++i) {               // stage pet0 -> H0 (persistent)
        int idx = i*256 + tid, rl = idx >> 4, c = idx & 15;
        f4 v = *(const f4*)((const char*)pet0 + (size_t)(rtile*64 + rl)*256 + c*16);
        *(f4*)(sm + H0 + hsw(rl, c)) = v;
      }
      __syncthreads();
      for (int s = chunk*2; s < chunk*2 + 2; ++s) {
        {
          h8 Bm[8];
          loadW(Bm, mfull + (size_t)s*16384, wbase, r15, hi);
          mmF4s(sm, H0, Bm, acc, r15, hi);        // di = pet0 @ Mfull_s
        }
        hw4r(sm, H1, wbase, acc, r15, hi);        // di -> H1 (input+skip)
        __syncthreads();
        LAYD(H1, H2, B0, 0); LAYD(H2, H3, B1, 128);
        LAYD(H3, H2, B2, 256); LAYD(H2, H3, B3, 384);
        mmF4s(sm, H3, B4, acc, r15, hi);          // decWout
        epi_direct(sm, H1, wbase, acc, bl,
                   out3 + ((size_t)rtile*64*50 + s)*128, 50*128, r15, hi);
        __syncthreads();                          // H1 skip reads done before next hw4r
      }
    }
  }
}

// ---------------- launch ----------------

extern "C" void kernel_launch(void* const* d_in, const int* in_sizes, int n_in,
                              void* d_out, int out_size, void* d_ws, size_t ws_size,
                              hipStream_t stream) {
  const float* x        = (const float*)d_in[0];
  const float* encW     = (const float*)d_in[1];
  const float* enc_b    = (const float*)d_in[2];
  const float* encWout  = (const float*)d_in[3];
  const float* enc_bout = (const float*)d_in[4];
  const float* decW     = (const float*)d_in[5];
  const float* dec_b    = (const float*)d_in[6];
  const float* decWout  = (const float*)d_in[7];
  const float* dec_bout = (const float*)d_in[8];
  const float* wencI    = (const float*)d_in[9];
  const float* L        = (const float*)d_in[10];
  const float* wdecI    = (const float*)d_in[11];

  char* ws = (char*)d_ws;
  _Float16* wt    = (_Float16*)ws;
  _Float16* mfull = (_Float16*)(ws + MFULL_OFF_B);
  float*    ach   = (float*)(ws + ACH_OFF_B);
  _Float16* pe_ws = (_Float16*)(ws + PE_OFF_B);
  _Float16* pet0  = (_Float16*)(ws + PET0_OFF_B);

  float* out1 = (float*)d_out;                       // autoencoder_output
  float* out2 = out1 + (size_t)ROWS_AUTO*128;        // outer_auto_output
  float* out3 = out2 + (size_t)ROWS_AUTO*128;        // predictions [2048][50][128]

  hipLaunchKernelGGL(k_prep, dim3(32, 11), dim3(512), 0, stream,
                     encW, encWout, decW, decWout, L, wt, ach);
  hipLaunchKernelGGL(k_aux, dim3(51), dim3(512), 0, stream,
                     ach, wencI, wdecI, mfull, wt);
  hipLaunchKernelGGL(k_enc, dim3(512), dim3(256), 0, stream,
                     x, wt, enc_b, enc_bout, pe_ws, pet0);
  hipLaunchKernelGGL(k_decpred, dim3(512), dim3(256), 0, stream,
                     wt, pe_ws, pet0, mfull, dec_b, dec_bout, out1, out2, out3);
}

// Round 19
// 197.126 us; speedup vs baseline: 1.1838x; 1.1526x over previous
//
#include <hip/hip_runtime.h>
#include <stdint.h>

// Koopman autoencoder — round 19 = R14 exact revert (MI355X / gfx950).
// Best verified: 199.3 us. Pinned per-wave weight slices (5 mats x 32 VGPR),
// direct f4 global stores from swapped-operand MFMA fragments (full sectors),
// f16 LDS-image pe intermediate, compact pet0, Mfull precompute for pred.
// R15-R18 structural variants (fences, tickets, dual-stream, prefetch+setprio)
// all measured worse; this is the local optimum of the family.

typedef _Float16 h8 __attribute__((ext_vector_type(8)));
typedef _Float16 h4 __attribute__((ext_vector_type(4)));
typedef float    f4 __attribute__((ext_vector_type(4)));

#define ROWS_AUTO 104448
#define NT64      1632           // 64-row dec tiles
#define NUNITS    2432           // 1632 dec + 800 pred (32 rtiles x 25 chunks x 2 steps)

// half-element offsets inside wt (all mats stored as W^T [n][k])
#define WT_ENCW      0
#define WT_ENCWOUT   (4*16384)
#define WT_DECW      (5*16384)
#define WT_DECWOUT   (9*16384)
#define WT_COMB      (10*16384)  // (WencI@WdecI)^T [128][128]

// ws byte offsets
#define MFULL_OFF_B 0x60000      // f16 [50][128][128] (WencI@L^{s+1}@WdecI)^T
#define ACH_OFF_B   0x200000     // f32 [50][441]
#define PE_OFF_B    0x220000     // f16 LDS-image tiles [1632][16384B]
#define PET0_OFF_B  0x1C00000    // f16 [2048][128] compact pe at t=0 (chunk-linear)

// LDS buffers (16KB each)
#define H0 0
#define H1 16384
#define H2 32768
#define H3 49152
#define LDSE (49152 + 2560)      // k_enc: H0..H2 + 640 f32 biases
#define LDSD (65536 + 2560)      // k_decpred: H0..H3 + 640 f32 biases

#define hsw(rl, c) ((rl)*256 + ((((c)) ^ ((rl) & 7)) << 4))

// opaque pin: forbids rematerialization/sinking of weight loads into the loop
#define PIN(B) asm volatile("" : "+v"(B[0]), "+v"(B[1]), "+v"(B[2]), "+v"(B[3]), \
                                 "+v"(B[4]), "+v"(B[5]), "+v"(B[6]), "+v"(B[7]))

__device__ __forceinline__ f4 mfma16(h8 a, h8 b, f4 c) {
  return __builtin_amdgcn_mfma_f32_16x16x32_f16(a, b, c, 0, 0, 0);
}
__device__ __forceinline__ h8 cvt8(f4 a, f4 b) {
  h8 r;
  r[0]=(_Float16)a[0]; r[1]=(_Float16)a[1]; r[2]=(_Float16)a[2]; r[3]=(_Float16)a[3];
  r[4]=(_Float16)b[0]; r[5]=(_Float16)b[1]; r[6]=(_Float16)b[2]; r[7]=(_Float16)b[3];
  return r;
}
// wave's 32-col slice of a 128x128 W^T
__device__ __forceinline__ void loadW(h8 B[8], const _Float16* gW, int nbase, int r15, int hi) {
#pragma unroll
  for (int nt = 0; nt < 2; ++nt)
#pragma unroll
    for (int ks = 0; ks < 4; ++ks)
      B[nt*4+ks] = *(const h8*)(gW + (size_t)(nbase + nt*16 + r15)*128 + ks*32 + hi*8);
}

// SWAPPED operands: lane holds out[row=rt*16+r15][n=wbase+nt*16+hi*4+d]
__device__ __forceinline__ void mmF4s(const char* sm, int hb, const h8 B[8],
                                      f4 acc[4][2], int r15, int hi) {
#pragma unroll
  for (int rt = 0; rt < 4; ++rt) { acc[rt][0] = (f4){0,0,0,0}; acc[rt][1] = (f4){0,0,0,0}; }
#pragma unroll
  for (int ks = 0; ks < 4; ++ks) {
    int c = ks*4 + hi;
    h8 a[4];
#pragma unroll
    for (int rt = 0; rt < 4; ++rt) a[rt] = *(const h8*)(sm + hb + hsw(rt*16 + r15, c));
#pragma unroll
    for (int rt = 0; rt < 4; ++rt) {
      acc[rt][0] = mfma16(B[ks],   a[rt], acc[rt][0]);
      acc[rt][1] = mfma16(B[4+ks], a[rt], acc[rt][1]);
    }
  }
}

// ReLU(acc + bias) -> h[hb] via b64 writes
__device__ __forceinline__ void hw4s(char* sm, int hb, int wbase, const f4 acc[4][2],
                                     const float* bl, int bo, int r15, int hi) {
  f4 bb0 = *(const f4*)(bl + bo + wbase + hi*4);
  f4 bb1 = *(const f4*)(bl + bo + wbase + 16 + hi*4);
  int bo2 = (hi & 1) * 8;
#pragma unroll
  for (int nt = 0; nt < 2; ++nt) {
    int c = ((wbase + nt*16) >> 3) + (hi >> 1);
    f4 bb = nt ? bb1 : bb0;
#pragma unroll
    for (int rt = 0; rt < 4; ++rt) {
      int row = rt*16 + r15;
      h4 p;
#pragma unroll
      for (int d = 0; d < 4; ++d) p[d] = (_Float16)fmaxf(acc[rt][nt][d] + bb[d], 0.f);
      *(h4*)(sm + hb + row*256 + ((c ^ (row & 7)) << 4) + bo2) = p;
    }
  }
}
// raw acc -> h[hb] (no bias/relu)
__device__ __forceinline__ void hw4r(char* sm, int hb, int wbase, const f4 acc[4][2],
                                     int r15, int hi) {
  int bo2 = (hi & 1) * 8;
#pragma unroll
  for (int nt = 0; nt < 2; ++nt) {
    int c = ((wbase + nt*16) >> 3) + (hi >> 1);
#pragma unroll
    for (int rt = 0; rt < 4; ++rt) {
      int row = rt*16 + r15;
      h4 p;
#pragma unroll
      for (int d = 0; d < 4; ++d) p[d] = (_Float16)acc[rt][nt][d];
      *(h4*)(sm + hb + row*256 + ((c ^ (row & 7)) << 4) + bo2) = p;
    }
  }
}

// DIRECT epilogue: out = acc + bout + skip(LDS) -> f4 global (full sectors, no barriers)
__device__ __forceinline__ void epi_direct(const char* sm, int hskip, int wbase,
                                           const f4 acc[4][2], const float* bl,
                                           float* dst, int rstride, int r15, int hi) {
  f4 bb0 = *(const f4*)(bl + 512 + wbase + hi*4);
  f4 bb1 = *(const f4*)(bl + 512 + wbase + 16 + hi*4);
  int bo2 = (hi & 1) * 8;
#pragma unroll
  for (int nt = 0; nt < 2; ++nt) {
    int c = ((wbase + nt*16) >> 3) + (hi >> 1);
    int n0 = wbase + nt*16 + hi*4;
    f4 bb = nt ? bb1 : bb0;
#pragma unroll
    for (int rt = 0; rt < 4; ++rt) {
      int row = rt*16 + r15;
      h4 sk = *(const h4*)(sm + hskip + row*256 + ((c ^ (row & 7)) << 4) + bo2);
      f4 v;
#pragma unroll
      for (int d = 0; d < 4; ++d) v[d] = acc[rt][nt][d] + bb[d] + (float)sk[d];
      *(f4*)(dst + (size_t)row*rstride + n0) = v;
    }
  }
}

#define LAYD(HIN, HOUT, BW, BO) do {                                 \
    mmF4s(sm, HIN, BW, acc, r15, hi);                                \
    hw4s(sm, HOUT, wbase, acc, bl, BO, r15, hi);                     \
    __syncthreads();                                                 \
  } while (0)

// ---------------- prep kernels ----------------

__global__ __launch_bounds__(512) void k_prep(
    const float* __restrict__ encW, const float* __restrict__ encWout,
    const float* __restrict__ decW, const float* __restrict__ decWout,
    const float* __restrict__ L,
    _Float16* __restrict__ wt, float* __restrict__ ach) {
  __shared__ float chA[441], chB[441];
  int m = blockIdx.y, tid = threadIdx.x;
  if (m == 10) {
    if (blockIdx.x != 0) return;
    if (tid < 441) chA[tid] = L[tid];
    __syncthreads();
    for (int s = 0; s < 50; ++s) {
      if (tid < 441) ach[s*441 + tid] = chA[tid];
      if (s == 49) break;
      if (tid < 441) {
        int i = tid / 21, j = tid % 21; float a = 0.f;
        for (int k = 0; k < 21; ++k) a += chA[i*21 + k] * L[k*21 + j];
        chB[tid] = a;
      }
      __syncthreads();
      if (tid < 441) chA[tid] = chB[tid];
      __syncthreads();
    }
    return;
  }
  int idx = blockIdx.x*512 + tid;
  if (idx >= 16384) return;
  const float* src; _Float16* dst;
  if (m < 4)       { src = encW + m*16384;     dst = wt + WT_ENCW + m*16384; }
  else if (m == 4) { src = encWout;            dst = wt + WT_ENCWOUT; }
  else if (m < 9)  { src = decW + (m-5)*16384; dst = wt + WT_DECW + (m-5)*16384; }
  else             { src = decWout;            dst = wt + WT_DECWOUT; }
  int n = idx >> 7, k = idx & 127;
  dst[idx] = (_Float16)src[k*128 + n];            // W^T[n][k]
}

__global__ __launch_bounds__(512) void k_aux(
    const float* __restrict__ ach, const float* __restrict__ wencI,
    const float* __restrict__ wdecI,
    _Float16* __restrict__ mfull, _Float16* __restrict__ wt) {
  __shared__ float T1[2688];
  __shared__ float sa[441];
  int s = blockIdx.x, t = threadIdx.x;
  if (s < 50) {
    if (t < 441) sa[t] = ach[s*441 + t];
    __syncthreads();
    for (int idx = t; idx < 2688; idx += 512) {
      int k = idx / 21, j = idx % 21;
      float a = 0.f;
      for (int u = 0; u < 21; ++u) a += wencI[k*21 + u] * sa[u*21 + j];
      T1[idx] = a;
    }
  } else {
    for (int idx = t; idx < 2688; idx += 512) T1[idx] = wencI[idx];
  }
  __syncthreads();
  _Float16* dst = (s < 50) ? (mfull + (size_t)s*16384) : (wt + WT_COMB);
  for (int idx = t; idx < 16384; idx += 512) {    // M^T[n][k]
    int n = idx >> 7, k = idx & 127;
    float a = 0.f;
    for (int j = 0; j < 21; ++j) a += T1[k*21 + j] * wdecI[j*128 + n];
    dst[idx] = (_Float16)a;
  }
}

// ---------------- encoder: x -> pe image + compact pet0 ----------------

__global__ __launch_bounds__(256, 2) void k_enc(
    const float* __restrict__ x, const _Float16* __restrict__ wt,
    const float* __restrict__ enc_b, const float* __restrict__ enc_bout,
    _Float16* __restrict__ pe_ws, _Float16* __restrict__ pet0) {
  __shared__ char sm[LDSE];
  float* bl = (float*)(sm + 49152);
  int tid = threadIdx.x, lane = tid & 63;
  int r15 = lane & 15, hi = lane >> 4;
  int wbase = (tid >> 6) * 32;
  h8 B0[8], B1[8], B2[8], B3[8], B4[8];
  loadW(B0, wt + WT_ENCW,           wbase, r15, hi);
  loadW(B1, wt + WT_ENCW + 16384,   wbase, r15, hi);
  loadW(B2, wt + WT_ENCW + 2*16384, wbase, r15, hi);
  loadW(B3, wt + WT_ENCW + 3*16384, wbase, r15, hi);
  loadW(B4, wt + WT_ENCWOUT,        wbase, r15, hi);
  PIN(B0); PIN(B1); PIN(B2); PIN(B3); PIN(B4);
  bl[tid] = enc_b[tid]; bl[256 + tid] = enc_b[256 + tid];
  if (tid < 128) bl[512 + tid] = enc_bout[tid];
  f4 acc[4][2];

  for (int t = blockIdx.x; t < NT64; t += gridDim.x) {
    size_t rb = (size_t)t * 64;
#pragma unroll
    for (int i = 0; i < 4; ++i) {                 // stage x -> H0 (enc skip)
      int idx = i*256 + tid, rl = idx >> 4, c = idx & 15;
      const float* s = x + (rb + rl)*128 + c*8;
      f4 v0 = *(const f4*)s, v1 = *(const f4*)(s + 4);
      *(h8*)(sm + H0 + hsw(rl, c)) = cvt8(v0, v1);
    }
    __syncthreads();
    LAYD(H0, H1, B0, 0); LAYD(H1, H2, B1, 128);
    LAYD(H2, H1, B2, 256); LAYD(H1, H2, B3, 384);
    mmF4s(sm, H2, B4, acc, r15, hi);              // encWout
    {                                             // pe = acc + bout + x, in-place H0
      f4 bb0 = *(const f4*)(bl + 512 + wbase + hi*4);
      f4 bb1 = *(const f4*)(bl + 512 + wbase + 16 + hi*4);
      int bo2 = (hi & 1) * 8;
#pragma unroll
      for (int nt = 0; nt < 2; ++nt) {
        int c = ((wbase + nt*16) >> 3) + (hi >> 1);
        f4 bb = nt ? bb1 : bb0;
#pragma unroll
        for (int rt = 0; rt < 4; ++rt) {
          int row = rt*16 + r15;
          int soff = H0 + row*256 + ((c ^ (row & 7)) << 4) + bo2;
          h4 sk = *(const h4*)(sm + soff);
          h4 p;
#pragma unroll
          for (int d = 0; d < 4; ++d) p[d] = (_Float16)(acc[rt][nt][d] + bb[d] + (float)sk[d]);
          *(h4*)(sm + soff) = p;                  // lane-private slot: no race
        }
      }
    }
    __syncthreads();
    {                                             // dump pe image + compact pet0
      char* g = (char*)(pe_ws) + (size_t)t*16384;
#pragma unroll
      for (int i = 0; i < 4; ++i) {
        int idx = i*256 + tid, off = idx*16;
        f4 v = *(const f4*)(sm + H0 + off);
        *(f4*)(g + off) = v;
        int rl = idx >> 4, slot = idx & 15;
        size_t rg = rb + (size_t)rl;
        if (rg % 51u == 0u) {
          int c = slot ^ (rl & 7);                // unswizzle -> chunk-linear
          *(f4*)((char*)pet0 + (rg/51u)*256 + c*16) = v;
        }
      }
    }
    __syncthreads();                              // dump reads done before next tile
  }
}

// ---------------- dec tiles + pred units (direct-store epilogues) ----------------

__global__ __launch_bounds__(256, 2) void k_decpred(
    const _Float16* __restrict__ wt, const _Float16* __restrict__ pe_ws,
    const _Float16* __restrict__ pet0, const _Float16* __restrict__ mfull,
    const float* __restrict__ dec_b, const float* __restrict__ dec_bout,
    float* __restrict__ out1, float* __restrict__ out2, float* __restrict__ out3) {
  __shared__ char sm[LDSD];
  float* bl = (float*)(sm + 65536);
  int tid = threadIdx.x, lane = tid & 63;
  int r15 = lane & 15, hi = lane >> 4;
  int wbase = (tid >> 6) * 32;
  h8 B0[8], B1[8], B2[8], B3[8], B4[8];
  loadW(B0, wt + WT_DECW,           wbase, r15, hi);
  loadW(B1, wt + WT_DECW + 16384,   wbase, r15, hi);
  loadW(B2, wt + WT_DECW + 2*16384, wbase, r15, hi);
  loadW(B3, wt + WT_DECW + 3*16384, wbase, r15, hi);
  loadW(B4, wt + WT_DECWOUT,        wbase, r15, hi);
  PIN(B0); PIN(B1); PIN(B2); PIN(B3); PIN(B4);
  bl[tid] = dec_b[tid]; bl[256 + tid] = dec_b[256 + tid];
  if (tid < 128) bl[512 + tid] = dec_bout[tid];
  f4 acc[4][2];

  for (int u = blockIdx.x; u < NUNITS; u += gridDim.x) {
    __syncthreads();                              // protect h bufs across units
    if (u < NT64) {
      // ---------- dec tile: pe -> out2 ; pd = pe@comb -> dec -> out1 ----------
      const char* src = (const char*)pe_ws + (size_t)u*16384;
#pragma unroll
      for (int i = 0; i < 4; ++i) {               // stage pe -> H0 (input+skip)
        int off = (i*256 + tid)*16;
        *(f4*)(sm + H0 + off) = *(const f4*)(src + off);
      }
      __syncthreads();
      LAYD(H0, H1, B0, 0); LAYD(H1, H2, B1, 128);
      LAYD(H2, H1, B2, 256); LAYD(H1, H2, B3, 384);
      mmF4s(sm, H2, B4, acc, r15, hi);            // decWout
      epi_direct(sm, H0, wbase, acc, bl,
                 out2 + (size_t)u*64*128, 128, r15, hi);   // no barrier
      {                                           // pd = pe @ comb (transient regs)
        h8 Bc[8];
        loadW(Bc, wt + WT_COMB, wbase, r15, hi);
        mmF4s(sm, H0, Bc, acc, r15, hi);
      }
      hw4r(sm, H3, wbase, acc, r15, hi);          // pd -> H3 (input+skip)
      __syncthreads();
      LAYD(H3, H0, B0, 0); LAYD(H0, H1, B1, 128);
      LAYD(H1, H0, B2, 256); LAYD(H0, H1, B3, 384);
      mmF4s(sm, H1, B4, acc, r15, hi);            // decWout
      epi_direct(sm, H3, wbase, acc, bl,
                 out1 + (size_t)u*64*128, 128, r15, hi);   // no barrier
    } else {
      // ---------- pred unit: pet0 rtile x 2 Koopman steps ----------
      int p = u - NT64, rtile = p / 25, chunk = p % 25;
#pragma unroll
      for (int i = 0; i < 4; ++i) {               // stage pet0 -> H0 (persistent)
        int idx = i*256 + tid, rl = idx >> 4, c = idx & 15;
        f4 v = *(const f4*)((const char*)pet0 + (size_t)(rtile*64 + rl)*256 + c*16);
        *(f4*)(sm + H0 + hsw(rl, c)) = v;
      }
      __syncthreads();
      for (int s = chunk*2; s < chunk*2 + 2; ++s) {
        {
          h8 Bm[8];
          loadW(Bm, mfull + (size_t)s*16384, wbase, r15, hi);
          mmF4s(sm, H0, Bm, acc, r15, hi);        // di = pet0 @ Mfull_s
        }
        hw4r(sm, H1, wbase, acc, r15, hi);        // di -> H1 (input+skip)
        __syncthreads();
        LAYD(H1, H2, B0, 0); LAYD(H2, H3, B1, 128);
        LAYD(H3, H2, B2, 256); LAYD(H2, H3, B3, 384);
        mmF4s(sm, H3, B4, acc, r15, hi);          // decWout
        epi_direct(sm, H1, wbase, acc, bl,
                   out3 + ((size_t)rtile*64*50 + s)*128, 50*128, r15, hi);
        __syncthreads();                          // H1 skip reads done before next hw4r
      }
    }
  }
}

// ---------------- launch ----------------

extern "C" void kernel_launch(void* const* d_in, const int* in_sizes, int n_in,
                              void* d_out, int out_size, void* d_ws, size_t ws_size,
                              hipStream_t stream) {
  const float* x        = (const float*)d_in[0];
  const float* encW     = (const float*)d_in[1];
  const float* enc_b    = (const float*)d_in[2];
  const float* encWout  = (const float*)d_in[3];
  const float* enc_bout = (const float*)d_in[4];
  const float* decW     = (const float*)d_in[5];
  const float* dec_b    = (const float*)d_in[6];
  const float* decWout  = (const float*)d_in[7];
  const float* dec_bout = (const float*)d_in[8];
  const float* wencI    = (const float*)d_in[9];
  const float* L        = (const float*)d_in[10];
  const float* wdecI    = (const float*)d_in[11];

  char* ws = (char*)d_ws;
  _Float16* wt    = (_Float16*)ws;
  _Float16* mfull = (_Float16*)(ws + MFULL_OFF_B);
  float*    ach   = (float*)(ws + ACH_OFF_B);
  _Float16* pe_ws = (_Float16*)(ws + PE_OFF_B);
  _Float16* pet0  = (_Float16*)(ws + PET0_OFF_B);

  float* out1 = (float*)d_out;                       // autoencoder_output
  float* out2 = out1 + (size_t)ROWS_AUTO*128;        // outer_auto_output
  float* out3 = out2 + (size_t)ROWS_AUTO*128;        // predictions [2048][50][128]

  hipLaunchKernelGGL(k_prep, dim3(32, 11), dim3(512), 0, stream,
                     encW, encWout, decW, decWout, L, wt, ach);
  hipLaunchKernelGGL(k_aux, dim3(51), dim3(512), 0, stream,
                     ach, wencI, wdecI, mfull, wt);
  hipLaunchKernelGGL(k_enc, dim3(512), dim3(256), 0, stream,
                     x, wt, enc_b, enc_bout, pe_ws, pet0);
  hipLaunchKernelGGL(k_decpred, dim3(512), dim3(256), 0, stream,
                     wt, pe_ws, pet0, mfull, dec_b, dec_bout, out1, out2, out3);
}